// Round 6
// baseline (663.311 us; speedup 1.0000x reference)
//
#include <hip/hip_runtime.h>
#include <hip/hip_bf16.h>

#define TT_    8
#define HEADS_ 8
#define NB_    147
#define NPIX   32768                // 8*64*64
#define NTASK  (NPIX*NB_)           // 4,816,896
#define ROWS_  (NPIX + 512)         // x rows + W rows, concatenated for prepack

typedef _Float16 half8 __attribute__((ext_vector_type(8)));
typedef _Float16 h2    __attribute__((ext_vector_type(2)));
typedef float    f32x4 __attribute__((ext_vector_type(4)));

__device__ __forceinline__ int reflect64(int v) {
  int m = v % 126;
  m += (m >> 31) & 126;             // floor-mod into [0,126)
  return (m > 63) ? (126 - m) : m;
}

__device__ __forceinline__ float dot2f(h2 a, h2 b, float c) {
#if __has_builtin(__builtin_amdgcn_fdot2)
  return __builtin_amdgcn_fdot2(a, b, c, false);
#else
  return c + (float)a[0]*(float)b[0] + (float)a[1]*(float)b[1];
#endif
}

// DPP quad-perm cross-lane adds (within aligned quads of 4 lanes).
__device__ __forceinline__ float dpp_xor1(float x) {
  int r = __builtin_amdgcn_mov_dpp(__builtin_bit_cast(int, x), 0xB1, 0xF, 0xF, true);
  return __builtin_bit_cast(float, r);
}
__device__ __forceinline__ float dpp_xor2(float x) {
  int r = __builtin_amdgcn_mov_dpp(__builtin_bit_cast(int, x), 0x4E, 0xF, 0xF, true);
  return __builtin_bit_cast(float, r);
}

// ---- Kernel 0: prepack x||W (rows x 256 f32) into fragment-native f16 ----
// 16B chunk id o: r=o&15, quad=(o>>4)&3, ks=(o>>6)&7, mt=o>>9.
// Chunk holds row (mt*16+r), cols [(ks*4+quad)*8, +8) as f16.
__global__ __launch_bounds__(256) void prepack(
    const float* __restrict__ x, const float* __restrict__ wqk,
    _Float16* __restrict__ outp) {
  int o  = (int)blockIdx.x * 256 + (int)threadIdx.x;   // 0 .. ROWS_*32
  int r  = o & 15, quad = (o >> 4) & 3, ks = (o >> 6) & 7, mt = o >> 9;
  int row = mt * 16 + r;
  const float* src = (row < NPIX) ? (x + (size_t)row * 256)
                                  : (wqk + (size_t)(row - NPIX) * 256);
  int col = (ks * 4 + quad) * 8;
  float4 a = *(const float4*)(src + col);
  float4 b = *(const float4*)(src + col + 4);
  half8 h;
  h[0]=(_Float16)a.x; h[1]=(_Float16)a.y; h[2]=(_Float16)a.z; h[3]=(_Float16)a.w;
  h[4]=(_Float16)b.x; h[5]=(_Float16)b.y; h[6]=(_Float16)b.z; h[7]=(_Float16)b.w;
  ((half8*)outp)[o] = h;
}

// ---- Kernel 1: qk GEMM, 64x64 per wave (4x4 MFMA sub-tiles) ----
__global__ __launch_bounds__(256) void qk_gemm(
    const _Float16* __restrict__ Ap,
    _Float16* __restrict__ qws, _Float16* __restrict__ kws) {
  const half8* A8 = (const half8*)Ap;
  const half8* B8 = (const half8*)(Ap + (size_t)NPIX * 256);
  int bid  = (int)blockIdx.x;
  int mblk = bid >> 2, nblk = bid & 3;
  int lane = (int)threadIdx.x & 63, wv = (int)threadIdx.x >> 6;
  int wm = mblk * 128 + (wv >> 1) * 64;
  int wn = nblk * 128 + (wv & 1) * 64;
  int r = lane & 15, quad = lane >> 4;

  f32x4 acc[4][4] = {};
#pragma unroll
  for (int ks = 0; ks < 8; ks++) {
    half8 af[4], bf[4];
#pragma unroll
    for (int im = 0; im < 4; im++)
      af[im] = A8[((((wm >> 4) + im) * 8 + ks) * 4 + quad) * 16 + r];
#pragma unroll
    for (int in = 0; in < 4; in++)
      bf[in] = B8[((((wn >> 4) + in) * 8 + ks) * 4 + quad) * 16 + r];
#pragma unroll
    for (int im = 0; im < 4; im++)
#pragma unroll
      for (int in = 0; in < 4; in++)
        acc[im][in] = __builtin_amdgcn_mfma_f32_16x16x32_f16(
            af[im], bf[in], acc[im][in], 0, 0, 0);
  }

  _Float16* dst = (wn < 256) ? qws : kws;
  int nsub = (wn < 256) ? 0 : 256;
#pragma unroll
  for (int im = 0; im < 4; im++)
#pragma unroll
    for (int in = 0; in < 4; in++) {
      int n = wn + in * 16 + r - nsub;
#pragma unroll
      for (int reg = 0; reg < 4; reg++) {
        int m = wm + im * 16 + quad * 4 + reg;
        dst[(size_t)m * 256 + n] = (_Float16)acc[im][in][reg];
      }
    }
}

// ---- Kernel 2: neighborhood attention (R5 structure, 4-deep k prefetch) ----
// Block = 256 tasks. Phase 1: one thread per task computes setup -> LDS.
// Phase 2: 8 lanes per task; iteration it computes from buffer it&3 while
// it+3's 4 k-chunk loads fill buffer (it+3)&3 (16 loads in flight; loads
// issued ~3 compute phases before use -> covers L2/L3 latency).
// Lane j reads chunk c*8+j: 4 consecutive lanes = one 64B line.
__global__ __launch_bounds__(256) void attn_kernel(
    const float* __restrict__ flows,
    const _Float16* __restrict__ qws, const _Float16* __restrict__ kws,
    float* __restrict__ out) {
  __shared__ int      s_info[256];
  __shared__ __attribute__((aligned(16))) _Float16 s_q[3 * 32 * 8];    // [pix][chunk 0..31][8 f16]
  __shared__ __attribute__((aligned(16))) float    s_attn[8 * 260];    // [head][task], pad 260
  __shared__ __attribute__((aligned(16))) float    s_flow[768];        // [task*3+c]

  // XCD swizzle: grid 18816 = 8*2352, contiguous task range per XCD.
  int nbq = (int)gridDim.x >> 3;
  int blk = ((int)blockIdx.x & 7) * nbq + ((int)blockIdx.x >> 3);
  int tx  = (int)threadIdx.x;
  int btid0 = blk * 256;
  int p0 = (int)((unsigned)btid0 / 147u);

  // ---- q staging loads issued EARLY (latency hides under phase-1 VALU) ----
  half8 vq = {};
  int qslot = -1;
  if (tx < 96) {
    int pix = tx >> 5, s = tx & 31;                    // s: 16B chunk of q row
    int p = p0 + pix; if (p > NPIX - 1) p = NPIX - 1;
    vq = *(const half8*)(qws + (size_t)p * 256 + s * 8);
    qslot = pix * 32 + s;
  }

  { // ---- phase 1: per-task setup (one thread per task) ----
    int tid = btid0 + tx;
    unsigned p = (unsigned)tid / 147u;
    int nb = tid - (int)(p * 147u);
    int t = (int)(p >> 12), hw = (int)(p & 4095u);
    int h = hw >> 6, w = hw & 63;
    int slot = nb / 49;
    int rr = nb - slot * 49;
    int a = rr / 7, b = rr - a * 7;
    int tp = t, di = 0, dj = 0;
    if (slot > 0) {
      int si = slot - 1;
      di = (int)rintf(flows[(size_t)((t * 2 + si) * 2 + 0) * 4096 + hw]);
      dj = (int)rintf(flows[(size_t)((t * 2 + si) * 2 + 1) * 4096 + hw]);
      tp = (slot == 1) ? ((t + 1 < TT_) ? t + 1 : t - 2)
                       : ((t - 1 >= 0)  ? t - 1 : t + 2);
    }
    int li = reflect64(h + di + a - 3);
    int lj = reflect64(w + dj + b - 3);
    int kidx = (tp << 12) + (li << 6) + lj;           // < 2^15
    int pixloc = (int)p - p0;                          // 0..2
    s_info[tx] = kidx | (pixloc << 20);
    s_flow[tx * 3 + 0] = (float)(tp - t);
    s_flow[tx * 3 + 1] = (float)(li - h);
    s_flow[tx * 3 + 2] = (float)(lj - w);
  }
  if (qslot >= 0) ((half8*)s_q)[qslot] = vq;
  __syncthreads();

  // ---- phase 2: 4-deep pipelined gather + dot ----
  int lane = tx & 63, wv = tx >> 6;
  int j = lane & 7, g = lane >> 3;
  const float scale = 0.17677669529663687f;            // 32^-0.5

  int infos[8];
#pragma unroll
  for (int it = 0; it < 8; it++) infos[it] = s_info[wv * 64 + it * 8 + g];

  half8 kb[4][4];                                      // 4 buffers x 4 chunks
#pragma unroll
  for (int pf = 0; pf < 3; pf++) {                     // prologue: it = 0,1,2
    const half8* kp = (const half8*)(kws + ((size_t)(infos[pf] & 0xFFFFF) << 8)) + j;
#pragma unroll
    for (int c = 0; c < 4; c++) kb[pf][c] = kp[c * 8];
  }
#pragma unroll
  for (int it = 0; it < 8; it++) {
    if (it < 5) {                                      // prefetch it+3
      const half8* kp = (const half8*)(kws + ((size_t)(infos[it + 3] & 0xFFFFF) << 8)) + j;
#pragma unroll
      for (int c = 0; c < 4; c++) kb[(it + 3) & 3][c] = kp[c * 8];
    }
    int pixloc = infos[it] >> 20;
    const half8* qp = ((const half8*)s_q) + pixloc * 32 + j;
    int tb = wv * 64 + it * 8 + g;
    float acc[4];
#pragma unroll
    for (int c = 0; c < 4; c++) {
      half8 k8 = kb[it & 3][c];
      half8 q8 = qp[c * 8];
      float s = 0.f;
#pragma unroll
      for (int u = 0; u < 8; u += 2) {
        h2 ka = { k8[u], k8[u + 1] };
        h2 qa = { q8[u], q8[u + 1] };
        s = dot2f(ka, qa, s);
      }
      acc[c] = s;
    }
#pragma unroll
    for (int c = 0; c < 4; c++) {
      float t = acc[c];
      t += dpp_xor1(t);
      t += dpp_xor2(t);                                // quad sum: full head dot
      if ((lane & 3) == 0)
        s_attn[(2 * c + ((lane >> 2) & 1)) * 260 + tb] = t * scale;
    }
  }
  __syncthreads();

  // ---- coalesced nontemporal stores from LDS (don't thrash L2 for k-gather) ----
  const f32x4* sa4 = (const f32x4*)s_attn;             // row stride 65 float4
#pragma unroll
  for (int o = 0; o < 2; o++) {
    int gg = tx + o * 256;                             // 0..511
    int hh = gg >> 6, idx = gg & 63;
    f32x4 v = sa4[hh * 65 + idx];
    __builtin_nontemporal_store(v, (f32x4*)(out + (size_t)hh * NTASK + btid0) + idx);
  }
  float* fo = out + (size_t)HEADS_ * NTASK;
  const f32x4* sf4 = (const f32x4*)s_flow;
#pragma unroll
  for (int o = 0; o < 6; o++) {
    int gg = tx + o * 256;                             // 0..1535
    int hh = gg / 192, idx = gg - hh * 192;
    f32x4 v = sf4[idx];
    __builtin_nontemporal_store(v, (f32x4*)(fo + (size_t)hh * NTASK * 3 + (size_t)btid0 * 3) + idx);
  }
}

extern "C" void kernel_launch(void* const* d_in, const int* in_sizes, int n_in,
                              void* d_out, int out_size, void* d_ws, size_t ws_size,
                              hipStream_t stream) {
  const float* x     = (const float*)d_in[0];   // (8,64,64,256) f32
  const float* flows = (const float*)d_in[1];   // (1,8,2,2,64,64) f32
  const float* wqk   = (const float*)d_in[2];   // (512,256) f32
  float* out = (float*)d_out;

  _Float16* qws = (_Float16*)d_ws;                       // 32768*256 f16
  _Float16* kws = qws + (size_t)NPIX * 256;              // 32768*256 f16
  _Float16* Ap  = kws + (size_t)NPIX * 256;              // 33280*256 f16 fragments

  prepack<<<dim3(ROWS_ * 32 / 256), dim3(256), 0, stream>>>(x, wqk, Ap);
  qk_gemm<<<dim3(1024), dim3(256), 0, stream>>>(Ap, qws, kws);
  attn_kernel<<<dim3(NTASK / 256), dim3(256), 0, stream>>>(flows, qws, kws, out);
}

// Round 7
// 653.564 us; speedup vs baseline: 1.0149x; 1.0149x over previous
//
#include <hip/hip_runtime.h>
#include <hip/hip_bf16.h>

#define TT_    8
#define HEADS_ 8
#define NB_    147
#define NPIX   32768                // 8*64*64
#define NTASK  (NPIX*NB_)           // 4,816,896
#define ROWS_  (NPIX + 512)         // x rows + W rows, concatenated for prepack

typedef _Float16 half8 __attribute__((ext_vector_type(8)));
typedef _Float16 h2    __attribute__((ext_vector_type(2)));
typedef float    f32x4 __attribute__((ext_vector_type(4)));

__device__ __forceinline__ int reflect64(int v) {
  int m = v % 126;
  m += (m >> 31) & 126;             // floor-mod into [0,126)
  return (m > 63) ? (126 - m) : m;
}

__device__ __forceinline__ float dot2f(h2 a, h2 b, float c) {
#if __has_builtin(__builtin_amdgcn_fdot2)
  return __builtin_amdgcn_fdot2(a, b, c, false);
#else
  return c + (float)a[0]*(float)b[0] + (float)a[1]*(float)b[1];
#endif
}

// DPP quad-perm cross-lane adds (within aligned quads of 4 lanes).
__device__ __forceinline__ float dpp_xor1(float x) {
  int r = __builtin_amdgcn_mov_dpp(__builtin_bit_cast(int, x), 0xB1, 0xF, 0xF, true);
  return __builtin_bit_cast(float, r);
}
__device__ __forceinline__ float dpp_xor2(float x) {
  int r = __builtin_amdgcn_mov_dpp(__builtin_bit_cast(int, x), 0x4E, 0xF, 0xF, true);
  return __builtin_bit_cast(float, r);
}

// ---- Kernel 0: prepack x||W (rows x 256 f32) into fragment-native f16 ----
// 16B chunk id o: r=o&15, quad=(o>>4)&3, ks=(o>>6)&7, mt=o>>9.
// Chunk holds row (mt*16+r), cols [(ks*4+quad)*8, +8) as f16.
__global__ __launch_bounds__(256) void prepack(
    const float* __restrict__ x, const float* __restrict__ wqk,
    _Float16* __restrict__ outp) {
  int o  = (int)blockIdx.x * 256 + (int)threadIdx.x;   // 0 .. ROWS_*32
  int r  = o & 15, quad = (o >> 4) & 3, ks = (o >> 6) & 7, mt = o >> 9;
  int row = mt * 16 + r;
  const float* src = (row < NPIX) ? (x + (size_t)row * 256)
                                  : (wqk + (size_t)(row - NPIX) * 256);
  int col = (ks * 4 + quad) * 8;
  float4 a = *(const float4*)(src + col);
  float4 b = *(const float4*)(src + col + 4);
  half8 h;
  h[0]=(_Float16)a.x; h[1]=(_Float16)a.y; h[2]=(_Float16)a.z; h[3]=(_Float16)a.w;
  h[4]=(_Float16)b.x; h[5]=(_Float16)b.y; h[6]=(_Float16)b.z; h[7]=(_Float16)b.w;
  ((half8*)outp)[o] = h;
}

// ---- Kernel 1: qk GEMM, 64x64 per wave (4x4 MFMA sub-tiles) ----
__global__ __launch_bounds__(256) void qk_gemm(
    const _Float16* __restrict__ Ap,
    _Float16* __restrict__ qws, _Float16* __restrict__ kws) {
  const half8* A8 = (const half8*)Ap;
  const half8* B8 = (const half8*)(Ap + (size_t)NPIX * 256);
  int bid  = (int)blockIdx.x;
  int mblk = bid >> 2, nblk = bid & 3;
  int lane = (int)threadIdx.x & 63, wv = (int)threadIdx.x >> 6;
  int wm = mblk * 128 + (wv >> 1) * 64;
  int wn = nblk * 128 + (wv & 1) * 64;
  int r = lane & 15, quad = lane >> 4;

  f32x4 acc[4][4] = {};
#pragma unroll
  for (int ks = 0; ks < 8; ks++) {
    half8 af[4], bf[4];
#pragma unroll
    for (int im = 0; im < 4; im++)
      af[im] = A8[((((wm >> 4) + im) * 8 + ks) * 4 + quad) * 16 + r];
#pragma unroll
    for (int in = 0; in < 4; in++)
      bf[in] = B8[((((wn >> 4) + in) * 8 + ks) * 4 + quad) * 16 + r];
#pragma unroll
    for (int im = 0; im < 4; im++)
#pragma unroll
      for (int in = 0; in < 4; in++)
        acc[im][in] = __builtin_amdgcn_mfma_f32_16x16x32_f16(
            af[im], bf[in], acc[im][in], 0, 0, 0);
  }

  _Float16* dst = (wn < 256) ? qws : kws;
  int nsub = (wn < 256) ? 0 : 256;
#pragma unroll
  for (int im = 0; im < 4; im++)
#pragma unroll
    for (int in = 0; in < 4; in++) {
      int n = wn + in * 16 + r - nsub;
#pragma unroll
      for (int reg = 0; reg < 4; reg++) {
        int m = wm + im * 16 + quad * 4 + reg;
        dst[(size_t)m * 256 + n] = (_Float16)acc[im][in][reg];
      }
    }
}

// ---- Kernel 2: neighborhood attention (R3 structure + 2-deep k prefetch) ----
// Block = 256 tasks. Phase 1: one thread per task computes setup -> LDS.
// Phase 2: 8 lanes per task; iteration it computes from register buffer A
// while it+1's 4 k-chunk loads fill buffer B (2-deep pipeline, 8 loads in
// flight). Lane j reads chunk c*8+j: 4 consecutive lanes = one 64B line.
__global__ __launch_bounds__(256) void attn_kernel(
    const float* __restrict__ flows,
    const _Float16* __restrict__ qws, const _Float16* __restrict__ kws,
    float* __restrict__ out) {
  __shared__ int      s_info[256];
  __shared__ __attribute__((aligned(16))) _Float16 s_q[3 * 32 * 8];    // [pix][chunk 0..31][8 f16]
  __shared__ __attribute__((aligned(16))) float    s_attn[8 * 260];    // [head][task], pad 260
  __shared__ __attribute__((aligned(16))) float    s_flow[768];        // [task*3+c]

  // XCD swizzle: grid 18816 = 8*2352, contiguous task range per XCD.
  int nbq = (int)gridDim.x >> 3;
  int blk = ((int)blockIdx.x & 7) * nbq + ((int)blockIdx.x >> 3);
  int tx  = (int)threadIdx.x;
  int btid0 = blk * 256;
  int p0 = (int)((unsigned)btid0 / 147u);

  // ---- q staging loads issued EARLY (latency hides under phase-1 VALU) ----
  half8 vq = {};
  int qslot = -1;
  if (tx < 96) {
    int pix = tx >> 5, s = tx & 31;                    // s: 16B chunk of q row
    int p = p0 + pix; if (p > NPIX - 1) p = NPIX - 1;
    vq = *(const half8*)(qws + (size_t)p * 256 + s * 8);
    qslot = pix * 32 + s;
  }

  { // ---- phase 1: per-task setup (one thread per task) ----
    int tid = btid0 + tx;
    unsigned p = (unsigned)tid / 147u;
    int nb = tid - (int)(p * 147u);
    int t = (int)(p >> 12), hw = (int)(p & 4095u);
    int h = hw >> 6, w = hw & 63;
    int slot = nb / 49;
    int rr = nb - slot * 49;
    int a = rr / 7, b = rr - a * 7;
    int tp = t, di = 0, dj = 0;
    if (slot > 0) {
      int si = slot - 1;
      di = (int)rintf(flows[(size_t)((t * 2 + si) * 2 + 0) * 4096 + hw]);
      dj = (int)rintf(flows[(size_t)((t * 2 + si) * 2 + 1) * 4096 + hw]);
      tp = (slot == 1) ? ((t + 1 < TT_) ? t + 1 : t - 2)
                       : ((t - 1 >= 0)  ? t - 1 : t + 2);
    }
    int li = reflect64(h + di + a - 3);
    int lj = reflect64(w + dj + b - 3);
    int kidx = (tp << 12) + (li << 6) + lj;           // < 2^15
    int pixloc = (int)p - p0;                          // 0..2
    s_info[tx] = kidx | (pixloc << 20);
    s_flow[tx * 3 + 0] = (float)(tp - t);
    s_flow[tx * 3 + 1] = (float)(li - h);
    s_flow[tx * 3 + 2] = (float)(lj - w);
  }
  if (qslot >= 0) ((half8*)s_q)[qslot] = vq;
  __syncthreads();

  // ---- phase 2: 2-deep pipelined gather + dot ----
  int lane = tx & 63, wv = tx >> 6;
  int j = lane & 7, g = lane >> 3;
  const float scale = 0.17677669529663687f;            // 32^-0.5

  int infos[8];
#pragma unroll
  for (int it = 0; it < 8; it++) infos[it] = s_info[wv * 64 + it * 8 + g];

  half8 kbA[4], kbB[4];
  {
    const half8* kp = (const half8*)(kws + ((size_t)(infos[0] & 0xFFFFF) << 8)) + j;
#pragma unroll
    for (int c = 0; c < 4; c++) kbA[c] = kp[c * 8];
  }
#pragma unroll
  for (int it = 0; it < 8; it++) {
    // prefetch it+1 into the other buffer (static selection after unroll)
    if (it < 7) {
      const half8* kp = (const half8*)(kws + ((size_t)(infos[it + 1] & 0xFFFFF) << 8)) + j;
      if ((it & 1) == 0) {
#pragma unroll
        for (int c = 0; c < 4; c++) kbB[c] = kp[c * 8];
      } else {
#pragma unroll
        for (int c = 0; c < 4; c++) kbA[c] = kp[c * 8];
      }
    }
    int pixloc = infos[it] >> 20;
    const half8* qp = ((const half8*)s_q) + pixloc * 32 + j;
    int tb = wv * 64 + it * 8 + g;
    float acc[4];
#pragma unroll
    for (int c = 0; c < 4; c++) {
      half8 k8 = ((it & 1) == 0) ? kbA[c] : kbB[c];
      half8 q8 = qp[c * 8];
      float s = 0.f;
#pragma unroll
      for (int u = 0; u < 8; u += 2) {
        h2 ka = { k8[u], k8[u + 1] };
        h2 qa = { q8[u], q8[u + 1] };
        s = dot2f(ka, qa, s);
      }
      acc[c] = s;
    }
#pragma unroll
    for (int c = 0; c < 4; c++) {
      float t = acc[c];
      t += dpp_xor1(t);
      t += dpp_xor2(t);                                // quad sum: full head dot
      if ((lane & 3) == 0)
        s_attn[(2 * c + ((lane >> 2) & 1)) * 260 + tb] = t * scale;
    }
  }
  __syncthreads();

  // ---- coalesced nontemporal stores from LDS (don't thrash L2 for k-gather) ----
  const f32x4* sa4 = (const f32x4*)s_attn;             // row stride 65 float4
#pragma unroll
  for (int o = 0; o < 2; o++) {
    int gg = tx + o * 256;                             // 0..511
    int hh = gg >> 6, idx = gg & 63;
    f32x4 v = sa4[hh * 65 + idx];
    __builtin_nontemporal_store(v, (f32x4*)(out + (size_t)hh * NTASK + btid0) + idx);
  }
  float* fo = out + (size_t)HEADS_ * NTASK;
  const f32x4* sf4 = (const f32x4*)s_flow;
#pragma unroll
  for (int o = 0; o < 6; o++) {
    int gg = tx + o * 256;                             // 0..1535
    int hh = gg / 192, idx = gg - hh * 192;
    f32x4 v = sf4[idx];
    __builtin_nontemporal_store(v, (f32x4*)(fo + (size_t)hh * NTASK * 3 + (size_t)btid0 * 3) + idx);
  }
}

extern "C" void kernel_launch(void* const* d_in, const int* in_sizes, int n_in,
                              void* d_out, int out_size, void* d_ws, size_t ws_size,
                              hipStream_t stream) {
  const float* x     = (const float*)d_in[0];   // (8,64,64,256) f32
  const float* flows = (const float*)d_in[1];   // (1,8,2,2,64,64) f32
  const float* wqk   = (const float*)d_in[2];   // (512,256) f32
  float* out = (float*)d_out;

  _Float16* qws = (_Float16*)d_ws;                       // 32768*256 f16
  _Float16* kws = qws + (size_t)NPIX * 256;              // 32768*256 f16
  _Float16* Ap  = kws + (size_t)NPIX * 256;              // 33280*256 f16 fragments

  prepack<<<dim3(ROWS_ * 32 / 256), dim3(256), 0, stream>>>(x, wqk, Ap);
  qk_gemm<<<dim3(1024), dim3(256), 0, stream>>>(Ap, qws, kws);
  attn_kernel<<<dim3(NTASK / 256), dim3(256), 0, stream>>>(flows, qws, kws, out);
}